// Round 1
// baseline (358.117 us; speedup 1.0000x reference)
//
#include <hip/hip_runtime.h>
#include <hip/hip_bf16.h>

// Problem constants
#define D_   1024
#define H_   16
#define HD_  64
#define B_   2
#define N_   1024
#define NM_  2048   // B*N rows

// ws layout (float offsets). Total 3150848 floats = ~12.6 MB.
#define OFF_X    0                     // X (gelu output)  [2048][1024]
#define OFF_M    (NM_*D_)              // M = Wo*W2 merged [1024][1024]
#define OFF_HBAR (OFF_M + D_*D_)       // hbar (mean of h over n) [2][1024]
#define OFF_C    (OFF_HBAR + B_*D_)    // c vec per (b,head,e)     [2][1024]
#define OFF_BIAS (OFF_C + B_*D_)       // bias_vec = Wo @ fu_b2    [1024]

// ---------------------------------------------------------------------------
// K0: hbar[b,d] = (1/N) * sum_n h[b,n,d].  grid 128 (= B*64 n-chunks), 256 thr
// ---------------------------------------------------------------------------
__global__ __launch_bounds__(256) void k_hbar(const float* __restrict__ h,
                                              float* __restrict__ hbar) {
    int blk = blockIdx.x;
    int b = blk >> 6, chunk = blk & 63;
    int tid = threadIdx.x;
    const float* hb = h + (size_t)b * N_ * D_;
    int n0 = chunk * 16;
#pragma unroll
    for (int rep = 0; rep < 4; ++rep) {
        int d = rep * 256 + tid;
        float s = 0.f;
        for (int n = n0; n < n0 + 16; ++n) s += hb[(size_t)n * D_ + d];
        atomicAdd(&hbar[b * D_ + d], s * (1.0f / N_));
    }
}

// ---------------------------------------------------------------------------
// K1: meanfeat[b,he] = Wv[he,:] . hbar[b,:]  (kept in LDS), then
//     c[b,he=h*64+e] = fu_b1[h,e] + sum_k (W1[h,e,64+k]+W1[h,e,128+k])*mf[k]
// grid 32 (= B*H), 256 thr
// ---------------------------------------------------------------------------
__global__ __launch_bounds__(256) void k_cvec(const float* __restrict__ Wv,
                                              const float* __restrict__ fu_W1,
                                              const float* __restrict__ fu_b1,
                                              const float* __restrict__ hbar,
                                              float* __restrict__ cvec) {
    __shared__ float psum[64][4];
    __shared__ float mf[64];
    int b = blockIdx.x >> 4, hh = blockIdx.x & 15;
    int tid = threadIdx.x;
    int e = tid >> 2, sl = tid & 3;
    const float* wrow = Wv + (size_t)(hh * 64 + e) * 1024;
    const float* hb = hbar + b * 1024;
    float s = 0.f;
    int k0 = sl * 256;
    for (int k = k0; k < k0 + 256; ++k) s += wrow[k] * hb[k];
    psum[e][sl] = s;
    __syncthreads();
    if (tid < 64) mf[tid] = psum[tid][0] + psum[tid][1] + psum[tid][2] + psum[tid][3];
    __syncthreads();
    if (tid < 64) {
        const float* w1 = fu_W1 + (size_t)(hh * 64 + tid) * 192;
        float acc = fu_b1[hh * 64 + tid];
        for (int k = 0; k < 64; ++k) acc += (w1[64 + k] + w1[128 + k]) * mf[k];
        cvec[b * 1024 + hh * 64 + tid] = acc;
    }
}

// ---------------------------------------------------------------------------
// K2: M[e', he=h*64+e] = sum_f Wo[e', h*64+f] * fu_W2[h, f, e]
// grid (1024, 4), 256 thr
// ---------------------------------------------------------------------------
__global__ __launch_bounds__(256) void k_M(const float* __restrict__ Wo,
                                           const float* __restrict__ fu_W2,
                                           float* __restrict__ M) {
    __shared__ float wo_s[256];
    int ep = blockIdx.x;
    int chunk = blockIdx.y;
    int tid = threadIdx.x;
    int he = chunk * 256 + tid;
    int h = he >> 6, e = he & 63;
    wo_s[tid] = Wo[(size_t)ep * 1024 + chunk * 256 + tid];
    __syncthreads();
    int base = (tid >> 6) * 64;  // head-local offset in wo_s
    const float* w2 = fu_W2 + (size_t)h * 4096 + e;  // stride 64 over f
    float s = 0.f;
#pragma unroll 8
    for (int f = 0; f < 64; ++f) s += wo_s[base + f] * w2[f * 64];
    M[(size_t)ep * 1024 + he] = s;
}

// ---------------------------------------------------------------------------
// K2b: bias_vec[e'] = sum_c Wo[e', c] * fu_b2_flat[c].  grid 1024, 256 thr
// ---------------------------------------------------------------------------
__global__ __launch_bounds__(256) void k_bias(const float* __restrict__ Wo,
                                              const float* __restrict__ fu_b2,
                                              float* __restrict__ bias) {
    __shared__ float red[256];
    int ep = blockIdx.x;
    int tid = threadIdx.x;
    float s = 0.f;
    for (int c = tid; c < 1024; c += 256) s += Wo[(size_t)ep * 1024 + c] * fu_b2[c];
    red[tid] = s;
    __syncthreads();
    for (int w = 128; w > 0; w >>= 1) {
        if (tid < w) red[tid] += red[tid + w];
        __syncthreads();
    }
    if (tid == 0) bias[ep] = red[0];
}

// ---------------------------------------------------------------------------
// K3/K4: C = A[2048x1024] @ W[1024x1024]^T with epilogue.
// MODE 1: per-head 64x64 (fu_W1a) transform + c + exact GELU -> X  (K3)
// MODE 0: + bias_vec -> d_out                                      (K4)
// BM=128, BN=64, BK=16, 256 threads, 8x4 register tile. grid (16,16).
// ---------------------------------------------------------------------------
template <int MODE>
__global__ __launch_bounds__(256) void k_gemm(const float* __restrict__ A,
                                              const float* __restrict__ Wm,
                                              float* __restrict__ Cout,
                                              const float* __restrict__ fu_W1,
                                              const float* __restrict__ cvec,
                                              const float* __restrict__ bias) {
    // smem: main loop As[16][132] (0..2112) + Bs[16][68] (2112..3200)
    // epilogue (MODE 1): HFs[128][68] (0..8704) + W1s[64][68] (8704..13056)
    __shared__ __align__(16) float smem[13056];
    float* As = smem;
    float* Bs = smem + 2112;

    const int tid = threadIdx.x;
    const int tx = tid & 15;   // -> cols tx*4 .. +3
    const int ty = tid >> 4;   // -> rows ty*8 .. +7
    const int rowBase = blockIdx.x * 128;
    const int colBase = blockIdx.y * 64;

    const int ar = tid >> 2;        // staging row 0..63
    const int ak = (tid & 3) << 2;  // staging k 0,4,8,12
    const float* Ap0 = A + (size_t)(rowBase + ar) * 1024 + ak;
    const float* Ap1 = Ap0 + (size_t)64 * 1024;
    const float* Bp  = Wm + (size_t)(colBase + ar) * 1024 + ak;

    float acc[8][4];
#pragma unroll
    for (int i = 0; i < 8; ++i)
#pragma unroll
        for (int j = 0; j < 4; ++j) acc[i][j] = 0.f;

    float4 a0 = *(const float4*)(Ap0);
    float4 a1 = *(const float4*)(Ap1);
    float4 b0 = *(const float4*)(Bp);

    for (int k0 = 0; k0 < 1024; k0 += 16) {
        __syncthreads();
        As[(ak + 0) * 132 + ar] = a0.x;
        As[(ak + 1) * 132 + ar] = a0.y;
        As[(ak + 2) * 132 + ar] = a0.z;
        As[(ak + 3) * 132 + ar] = a0.w;
        As[(ak + 0) * 132 + 64 + ar] = a1.x;
        As[(ak + 1) * 132 + 64 + ar] = a1.y;
        As[(ak + 2) * 132 + 64 + ar] = a1.z;
        As[(ak + 3) * 132 + 64 + ar] = a1.w;
        Bs[(ak + 0) * 68 + ar] = b0.x;
        Bs[(ak + 1) * 68 + ar] = b0.y;
        Bs[(ak + 2) * 68 + ar] = b0.z;
        Bs[(ak + 3) * 68 + ar] = b0.w;
        // prefetch next K-slice; consumed after next barrier
        float4 na0 = a0, na1 = a1, nb0 = b0;
        if (k0 + 16 < 1024) {
            na0 = *(const float4*)(Ap0 + k0 + 16);
            na1 = *(const float4*)(Ap1 + k0 + 16);
            nb0 = *(const float4*)(Bp + k0 + 16);
        }
        __syncthreads();
#pragma unroll
        for (int kk = 0; kk < 16; ++kk) {
            float4 av0 = *(const float4*)&As[kk * 132 + ty * 8];
            float4 av1 = *(const float4*)&As[kk * 132 + ty * 8 + 4];
            float4 bv  = *(const float4*)&Bs[kk * 68 + tx * 4];
            float a_[8] = {av0.x, av0.y, av0.z, av0.w, av1.x, av1.y, av1.z, av1.w};
            float b_[4] = {bv.x, bv.y, bv.z, bv.w};
#pragma unroll
            for (int i = 0; i < 8; ++i)
#pragma unroll
                for (int j = 0; j < 4; ++j) acc[i][j] += a_[i] * b_[j];
        }
        a0 = na0; a1 = na1; b0 = nb0;
    }
    __syncthreads();

    if (MODE == 0) {
        float4 bj = *(const float4*)&bias[colBase + tx * 4];
#pragma unroll
        for (int i = 0; i < 8; ++i) {
            float4 v = make_float4(acc[i][0] + bj.x, acc[i][1] + bj.y,
                                   acc[i][2] + bj.z, acc[i][3] + bj.w);
            *(float4*)&Cout[(size_t)(rowBase + ty * 8 + i) * 1024 + colBase + tx * 4] = v;
        }
    } else {
        // Epilogue: X = gelu(HF @ W1a^T + c), block-diagonal per head.
        float* HFs = smem;         // [128][68]
        float* W1s = smem + 8704;  // [64][68]
#pragma unroll
        for (int i = 0; i < 8; ++i)
#pragma unroll
            for (int j = 0; j < 4; ++j)
                HFs[(ty * 8 + i) * 68 + tx * 4 + j] = acc[i][j];
        const int hh = colBase >> 6;
        for (int s = tid; s < 4096; s += 256) {
            int e = s >> 6, k = s & 63;
            W1s[e * 68 + k] = fu_W1[(size_t)(hh * 64 + e) * 192 + k];
        }
        __syncthreads();
        const int b = rowBase >> 10;
        float xs[8][4];
        {
            const float* cv = cvec + b * 1024 + colBase + tx * 4;
#pragma unroll
            for (int i = 0; i < 8; ++i)
#pragma unroll
                for (int j = 0; j < 4; ++j) xs[i][j] = cv[j];
        }
#pragma unroll
        for (int kq = 0; kq < 16; ++kq) {
            float4 w4[4];
#pragma unroll
            for (int j = 0; j < 4; ++j)
                w4[j] = *(const float4*)&W1s[(tx * 4 + j) * 68 + kq * 4];
#pragma unroll
            for (int i = 0; i < 8; ++i) {
                float4 h4 = *(const float4*)&HFs[(ty * 8 + i) * 68 + kq * 4];
#pragma unroll
                for (int j = 0; j < 4; ++j)
                    xs[i][j] += h4.x * w4[j].x + h4.y * w4[j].y +
                                h4.z * w4[j].z + h4.w * w4[j].w;
            }
        }
#pragma unroll
        for (int i = 0; i < 8; ++i) {
            float4 v;
            float* vp = &v.x;
#pragma unroll
            for (int j = 0; j < 4; ++j) {
                float t = xs[i][j];
                vp[j] = 0.5f * t * (1.0f + erff(t * 0.70710678118654752f));
            }
            *(float4*)&Cout[(size_t)(rowBase + ty * 8 + i) * 1024 + colBase + tx * 4] = v;
        }
    }
}

// ---------------------------------------------------------------------------
// K5: targets + strength tail outputs (all closed-form).
// ---------------------------------------------------------------------------
__global__ __launch_bounds__(256) void k_tail(const int* __restrict__ prev_idx,
                                              const float* __restrict__ chain_ratio,
                                              float* __restrict__ out) {
    int i = blockIdx.x * 256 + threadIdx.x;  // 0..2047 = b*1024 + n
    if (i >= 2048) return;
    int n = i & 1023;
    float cr = chain_ratio[0];
    float sig = 1.0f / (1.0f + expf(-cr));
    float thr = floorf(sig * 1024.0f);
    float fwd;
    if ((float)n >= thr) {
        int p = prev_idx[i];
        p = p < 0 ? 0 : (p > 1023 ? 1023 : p);
        fwd = (float)p;
    } else {
        fwd = 511.0f;  // int(sum((1/N)*pos)) = int(511.5), exact in f32
    }
    out[2097152 + i] = fwd;
    out[2097152 + 2048 + i] = 511.0f;
    out[2097152 + 4096 + i] = 1.0f - logf(1.0f / 1024.0f + 1e-8f);
}

// ---------------------------------------------------------------------------
extern "C" void kernel_launch(void* const* d_in, const int* in_sizes, int n_in,
                              void* d_out, int out_size, void* d_ws, size_t ws_size,
                              hipStream_t stream) {
    const float* h       = (const float*)d_in[0];
    const int*   prev    = (const int*)d_in[1];
    // d_in[2..9]: fw_*/bw_* encoder weights — provably unused (softmax over a
    // broadcast scalar is uniform 1/N regardless of logits).
    const float* Wv      = (const float*)d_in[10];
    const float* fu_W1   = (const float*)d_in[11];
    const float* fu_b1   = (const float*)d_in[12];
    const float* fu_W2   = (const float*)d_in[13];
    const float* fu_b2   = (const float*)d_in[14];
    const float* Wo      = (const float*)d_in[15];
    const float* cratio  = (const float*)d_in[16];

    float* out  = (float*)d_out;
    float* ws   = (float*)d_ws;
    float* Xw   = ws + OFF_X;
    float* Mw   = ws + OFF_M;
    float* hbar = ws + OFF_HBAR;
    float* cv   = ws + OFF_C;
    float* bias = ws + OFF_BIAS;

    hipMemsetAsync(hbar, 0, B_ * D_ * sizeof(float), stream);
    k_hbar<<<128, 256, 0, stream>>>(h, hbar);
    k_cvec<<<32, 256, 0, stream>>>(Wv, fu_W1, fu_b1, hbar, cv);
    k_M<<<dim3(1024, 4), 256, 0, stream>>>(Wo, fu_W2, Mw);
    k_bias<<<1024, 256, 0, stream>>>(Wo, fu_b2, bias);
    // GEMM1: HF = h @ Wv^T, fused per-head MLP layer1 + GELU -> X
    k_gemm<1><<<dim3(16, 16), 256, 0, stream>>>(h, Wv, Xw, fu_W1, cv, nullptr);
    // GEMM2: out = X @ M^T + bias  (fu_W2 and Wo pre-collapsed into M)
    k_gemm<0><<<dim3(16, 16), 256, 0, stream>>>(Xw, Mw, out, nullptr, nullptr, bias);
    k_tail<<<8, 256, 0, stream>>>(prev, cratio, out);
}

// Round 2
// 193.815 us; speedup vs baseline: 1.8477x; 1.8477x over previous
//
#include <hip/hip_runtime.h>
#include <hip/hip_bf16.h>

// Problem constants: D=1024, H=16, HD=64, B=2, N=1024, rows = B*N = 2048.

typedef __attribute__((ext_vector_type(8))) short bf16x8;
typedef __attribute__((ext_vector_type(4))) float f32x4;

// ws layout (float offsets). Total 2,659,328 floats = 10.6 MB (round-1 used 12.6 MB OK).
#define OFF_HBF  0                       // h cast to bf16      [2048][1024] (1M floats)
#define OFF_XBF  1048576                 // X (gelu out) bf16   [2048][1024] (1M floats)
#define OFF_WBF  2097152                 // Wv_bf, later reused for M_bf [1024][1024] (512K)
#define OFF_W1A  2621440                 // fu_W1 head-diag block bf16 [16][64][64] (32K)
#define OFF_HBAR 2654208                 // mean of h over n  [2][1024]
#define OFF_C    2656256                 // c vec per (b,head,e) [2][1024]
#define OFF_BIAS 2658304                 // bias_vec = Wo @ fu_b2 [1024]

__device__ __forceinline__ unsigned short f2bf(float f) {
    unsigned int u = __float_as_uint(f);
    u += 0x7fffu + ((u >> 16) & 1u);   // round-to-nearest-even
    return (unsigned short)(u >> 16);
}

__device__ __forceinline__ void async_load16(const void* g, void* l) {
    __builtin_amdgcn_global_load_lds(
        (const __attribute__((address_space(1))) unsigned int*)g,
        (__attribute__((address_space(3))) unsigned int*)l, 16, 0, 0);
}

// ---------------------------------------------------------------------------
// K0: cast h -> bf16 AND accumulate hbar[b,d] = (1/N) sum_n h[b,n,d].
// grid 128 (= B*64 chunks of 16 rows), 256 thr.
// ---------------------------------------------------------------------------
__global__ __launch_bounds__(256) void k_cast_h(const float* __restrict__ h,
                                                unsigned short* __restrict__ hbf,
                                                float* __restrict__ hbar) {
    int blk = blockIdx.x;
    int b = blk >> 6, chunk = blk & 63;
    int tid = threadIdx.x;
    const float* hb = h + (size_t)b * 1024 * 1024;
    unsigned short* ob = hbf + (size_t)b * 1024 * 1024;
    int n0 = chunk * 16;
#pragma unroll
    for (int rep = 0; rep < 4; ++rep) {
        int d = rep * 256 + tid;
        float s = 0.f;
        for (int n = n0; n < n0 + 16; ++n) {
            float v = hb[(size_t)n * 1024 + d];
            s += v;
            ob[(size_t)n * 1024 + d] = f2bf(v);
        }
        atomicAdd(&hbar[b * 1024 + d], s * (1.0f / 1024.0f));
    }
}

// ---------------------------------------------------------------------------
// K1: mf[b,he] = Wv[he,:].hbar[b,:]; c[b,he] = fu_b1 + sum_k (W1[.,64+k]+W1[.,128+k])*mf
// grid 32 (= B*H), 256 thr.  (fp32, tiny)
// ---------------------------------------------------------------------------
__global__ __launch_bounds__(256) void k_cvec(const float* __restrict__ Wv,
                                              const float* __restrict__ fu_W1,
                                              const float* __restrict__ fu_b1,
                                              const float* __restrict__ hbar,
                                              float* __restrict__ cvec) {
    __shared__ float psum[64][4];
    __shared__ float mf[64];
    int b = blockIdx.x >> 4, hh = blockIdx.x & 15;
    int tid = threadIdx.x;
    int e = tid >> 2, sl = tid & 3;
    const float* wrow = Wv + (size_t)(hh * 64 + e) * 1024;
    const float* hb = hbar + b * 1024;
    float s = 0.f;
    int k0 = sl * 256;
    for (int k = k0; k < k0 + 256; ++k) s += wrow[k] * hb[k];
    psum[e][sl] = s;
    __syncthreads();
    if (tid < 64) mf[tid] = psum[tid][0] + psum[tid][1] + psum[tid][2] + psum[tid][3];
    __syncthreads();
    if (tid < 64) {
        const float* w1 = fu_W1 + (size_t)(hh * 64 + tid) * 192;
        float acc = fu_b1[hh * 64 + tid];
        for (int k = 0; k < 64; ++k) acc += (w1[64 + k] + w1[128 + k]) * mf[k];
        cvec[b * 1024 + hh * 64 + tid] = acc;
    }
}

// ---------------------------------------------------------------------------
// K2: cast Wv -> bf16 (blocks 0..1023) and fu_W1[:, :, 0:64] -> W1a bf16
// (blocks 1024..1087). 256 thr, 4 elems each.
// ---------------------------------------------------------------------------
__global__ __launch_bounds__(256) void k_cast_w(const float* __restrict__ Wv,
                                                const float* __restrict__ fu_W1,
                                                unsigned short* __restrict__ Wvbf,
                                                unsigned short* __restrict__ W1abf) {
    int blk = blockIdx.x, tid = threadIdx.x;
    if (blk < 1024) {
        int i0 = blk * 1024 + tid * 4;
        float4 v = *(const float4*)(Wv + i0);
        ushort4 o = make_ushort4(f2bf(v.x), f2bf(v.y), f2bf(v.z), f2bf(v.w));
        *(ushort4*)(Wvbf + i0) = o;
    } else {
        int blk2 = blk - 1024;                 // 0..63
        int hh = blk2 >> 2, q = blk2 & 3;
        int e = q * 16 + (tid >> 4);
        int k4 = (tid & 15) * 4;
        float4 v = *(const float4*)(fu_W1 + (size_t)(hh * 64 + e) * 192 + k4);
        ushort4 o = make_ushort4(f2bf(v.x), f2bf(v.y), f2bf(v.z), f2bf(v.w));
        *(ushort4*)(W1abf + hh * 4096 + e * 64 + k4) = o;
    }
}

// ---------------------------------------------------------------------------
// K3: M_bf[e', he=h*64+e] = bf16( sum_f Wo[e', h*64+f] * fu_W2[h, f, e] )
// grid (1024, 4), 256 thr.
// ---------------------------------------------------------------------------
__global__ __launch_bounds__(256) void k_M(const float* __restrict__ Wo,
                                           const float* __restrict__ fu_W2,
                                           unsigned short* __restrict__ Mbf) {
    __shared__ float wo_s[256];
    int ep = blockIdx.x;
    int chunk = blockIdx.y;
    int tid = threadIdx.x;
    int he = chunk * 256 + tid;
    int h = he >> 6, e = he & 63;
    wo_s[tid] = Wo[(size_t)ep * 1024 + chunk * 256 + tid];
    __syncthreads();
    int base = (tid >> 6) * 64;
    const float* w2 = fu_W2 + (size_t)h * 4096 + e;   // stride 64 over f
    float s = 0.f;
#pragma unroll 8
    for (int f = 0; f < 64; ++f) s += wo_s[base + f] * w2[f * 64];
    Mbf[(size_t)ep * 1024 + he] = f2bf(s);
}

// ---------------------------------------------------------------------------
// K4: bias_vec[e'] = sum_c Wo[e', c] * fu_b2_flat[c].  grid 1024, 256 thr.
// ---------------------------------------------------------------------------
__global__ __launch_bounds__(256) void k_bias(const float* __restrict__ Wo,
                                              const float* __restrict__ fu_b2,
                                              float* __restrict__ bias) {
    __shared__ float red[256];
    int ep = blockIdx.x;
    int tid = threadIdx.x;
    float s = 0.f;
    for (int c = tid; c < 1024; c += 256) s += Wo[(size_t)ep * 1024 + c] * fu_b2[c];
    red[tid] = s;
    __syncthreads();
    for (int w = 128; w > 0; w >>= 1) {
        if (tid < w) red[tid] += red[tid + w];
        __syncthreads();
    }
    if (tid == 0) bias[ep] = red[0];
}

// ---------------------------------------------------------------------------
// K5/K6: bf16 MFMA GEMM, C = A[2048xK=1024] @ W[1024x1024]^T.
// BM=BN=64, BK=64, 256 thr (4 waves, each 32x32 = 2x2 16x16 tiles).
// grid (32,16) = 512 blocks = 2 blocks/CU.
// LDS: As[64][64] bf16 (8K, 128B rows) + Bs[64][64] (8K), XOR-swizzled:
//   byte(r,c) = r*128 + (((c>>3) ^ (r&7))<<4) + (c&7)*2  -> 2-way max conflict.
// global_load_lds(16B): wave covers 8 rows x 8 segs; lane i -> row i>>3, lds seg
//   i&7; source seg = (i&7)^(i>>3) realizes the swizzle on the gather side.
// MODE 1: epilogue = per-head 64x64 MLP (HF->LDS A-layout, W1a as B) + c +
//         exact GELU -> X bf16 (coalesced via LDS). MODE 0: + bias -> fp32 out.
// ---------------------------------------------------------------------------
template <int MODE>
__global__ __launch_bounds__(256) void k_mm(const unsigned short* __restrict__ A,
                                            const unsigned short* __restrict__ Bw,
                                            void* __restrict__ CoutV,
                                            const unsigned short* __restrict__ W1a,
                                            const float* __restrict__ cvec,
                                            const float* __restrict__ bias) {
    __shared__ __align__(16) char smem[16384];
    char* As = smem;
    char* Bs = smem + 8192;
    const int tid = threadIdx.x;
    const int w = tid >> 6, lane = tid & 63;
    const int rowBase = blockIdx.x * 64, colBase = blockIdx.y * 64;
    const int wmh = (w >> 1) * 32, wnh = (w & 1) * 32;
    const int lr = lane >> 3;             // row within 8-row staging chunk
    const int ssrc = ((lane & 7) ^ lr) * 8;  // source k element offset (swizzle)
    const int m_lane = lane & 15, quad = lane >> 4;

    const unsigned short* Ag0 = A + (size_t)(rowBase + w * 8 + lr) * 1024 + ssrc;
    const unsigned short* Ag1 = Ag0 + (size_t)32 * 1024;
    const unsigned short* Bg0 = Bw + (size_t)(colBase + w * 8 + lr) * 1024 + ssrc;
    const unsigned short* Bg1 = Bg0 + (size_t)32 * 1024;
    char* AsW = As + w * 1024;   // wave-uniform LDS staging bases
    char* BsW = Bs + w * 1024;

    f32x4 acc[2][2];
#pragma unroll
    for (int i = 0; i < 2; ++i)
#pragma unroll
        for (int j = 0; j < 2; ++j) acc[i][j] = (f32x4){0.f, 0.f, 0.f, 0.f};

    for (int k0 = 0; k0 < 1024; k0 += 64) {
        __syncthreads();                       // prev iter's frag reads done
        async_load16(Ag0 + k0, AsW);
        async_load16(Ag1 + k0, AsW + 4096);
        async_load16(Bg0 + k0, BsW);
        async_load16(Bg1 + k0, BsW + 4096);
        __syncthreads();                       // vmcnt(0) drain before barrier
#pragma unroll
        for (int kh = 0; kh < 2; ++kh) {
            const int seg = kh * 4 + quad;
            bf16x8 af[2], bfr[2];
#pragma unroll
            for (int mt = 0; mt < 2; ++mt) {
                int m = wmh + mt * 16 + m_lane;
                af[mt] = *(const bf16x8*)(As + m * 128 + ((seg ^ (m & 7)) << 4));
            }
#pragma unroll
            for (int nt = 0; nt < 2; ++nt) {
                int n = wnh + nt * 16 + m_lane;
                bfr[nt] = *(const bf16x8*)(Bs + n * 128 + ((seg ^ (n & 7)) << 4));
            }
#pragma unroll
            for (int mt = 0; mt < 2; ++mt)
#pragma unroll
                for (int nt = 0; nt < 2; ++nt)
                    acc[mt][nt] = __builtin_amdgcn_mfma_f32_16x16x32_bf16(
                        af[mt], bfr[nt], acc[mt][nt], 0, 0, 0);
        }
    }

    if (MODE == 0) {
        float* out = (float*)CoutV;
#pragma unroll
        for (int nt = 0; nt < 2; ++nt) {
            int c = colBase + wnh + nt * 16 + m_lane;
            float bj = bias[c];
#pragma unroll
            for (int mt = 0; mt < 2; ++mt)
#pragma unroll
                for (int r4 = 0; r4 < 4; ++r4) {
                    int r = rowBase + wmh + mt * 16 + quad * 4 + r4;
                    out[(size_t)r * 1024 + c] = acc[mt][nt][r4] + bj;
                }
        }
    } else {
        unsigned short* Xbf = (unsigned short*)CoutV;
        const int hh = blockIdx.y;             // head for this 64-col block
        __syncthreads();                       // main-loop LDS reads done
        // stage W1a head block [64 e_out][64 e_in] into Bs (swizzled, async)
        const unsigned short* Wg = W1a + hh * 4096 + (w * 8 + lr) * 64 + ssrc;
        async_load16(Wg, BsW);
        async_load16(Wg + 32 * 64, BsW + 4096);
        // write HF (bf16 of acc) into As in A-fragment (swizzled) layout
#pragma unroll
        for (int mt = 0; mt < 2; ++mt)
#pragma unroll
            for (int nt = 0; nt < 2; ++nt) {
                int c = wnh + nt * 16 + m_lane;
#pragma unroll
                for (int r4 = 0; r4 < 4; ++r4) {
                    int r = wmh + mt * 16 + quad * 4 + r4;
                    *(unsigned short*)(As + r * 128 + (((c >> 3) ^ (r & 7)) << 4) +
                                       (c & 7) * 2) = f2bf(acc[mt][nt][r4]);
                }
            }
        __syncthreads();
        f32x4 acc2[2][2];
#pragma unroll
        for (int i = 0; i < 2; ++i)
#pragma unroll
            for (int j = 0; j < 2; ++j) acc2[i][j] = (f32x4){0.f, 0.f, 0.f, 0.f};
#pragma unroll
        for (int kh = 0; kh < 2; ++kh) {
            const int seg = kh * 4 + quad;
            bf16x8 af[2], bfr[2];
#pragma unroll
            for (int mt = 0; mt < 2; ++mt) {
                int m = wmh + mt * 16 + m_lane;
                af[mt] = *(const bf16x8*)(As + m * 128 + ((seg ^ (m & 7)) << 4));
            }
#pragma unroll
            for (int nt = 0; nt < 2; ++nt) {
                int n = wnh + nt * 16 + m_lane;
                bfr[nt] = *(const bf16x8*)(Bs + n * 128 + ((seg ^ (n & 7)) << 4));
            }
#pragma unroll
            for (int mt = 0; mt < 2; ++mt)
#pragma unroll
                for (int nt = 0; nt < 2; ++nt)
                    acc2[mt][nt] = __builtin_amdgcn_mfma_f32_16x16x32_bf16(
                        af[mt], bfr[nt], acc2[mt][nt], 0, 0, 0);
        }
        __syncthreads();                       // HF reads done; As reusable
        const int b = rowBase >> 10;
#pragma unroll
        for (int mt = 0; mt < 2; ++mt)
#pragma unroll
            for (int nt = 0; nt < 2; ++nt) {
                int c = wnh + nt * 16 + m_lane;
                float cadd = cvec[b * 1024 + hh * 64 + c];
#pragma unroll
                for (int r4 = 0; r4 < 4; ++r4) {
                    int r = wmh + mt * 16 + quad * 4 + r4;
                    float t = acc2[mt][nt][r4] + cadd;
                    t = 0.5f * t * (1.0f + erff(t * 0.70710678118654752f));
                    *(unsigned short*)(As + r * 128 + c * 2) = f2bf(t);  // plain
                }
            }
        __syncthreads();
        // coalesced X store: 512 16B-segments, 2 per thread
#pragma unroll
        for (int j = 0; j < 2; ++j) {
            int seg = tid + j * 256;
            int r = seg >> 3, s = seg & 7;
            float4 v = *(const float4*)(As + r * 128 + s * 16);
            *(float4*)((char*)Xbf +
                       ((size_t)(rowBase + r) * 1024 + colBase + s * 8) * 2) = v;
        }
    }
}

// ---------------------------------------------------------------------------
// K7: targets + strength tail (closed-form: uniform softmax over broadcast
// scalar logit -> targets 511 / chained prev_idx, strength = 1 - ln(1/N+eps)).
// ---------------------------------------------------------------------------
__global__ __launch_bounds__(256) void k_tail(const int* __restrict__ prev_idx,
                                              const float* __restrict__ chain_ratio,
                                              float* __restrict__ out) {
    int i = blockIdx.x * 256 + threadIdx.x;  // 0..2047 = b*1024 + n
    if (i >= 2048) return;
    int n = i & 1023;
    float cr = chain_ratio[0];
    float sig = 1.0f / (1.0f + expf(-cr));
    float thr = floorf(sig * 1024.0f);
    float fwd;
    if ((float)n >= thr) {
        int p = prev_idx[i];
        p = p < 0 ? 0 : (p > 1023 ? 1023 : p);
        fwd = (float)p;
    } else {
        fwd = 511.0f;  // int(sum((1/N)*pos)) exact in f32
    }
    out[2097152 + i] = fwd;
    out[2097152 + 2048 + i] = 511.0f;
    out[2097152 + 4096 + i] = 1.0f - logf(1.0f / 1024.0f + 1e-8f);
}

// ---------------------------------------------------------------------------
extern "C" void kernel_launch(void* const* d_in, const int* in_sizes, int n_in,
                              void* d_out, int out_size, void* d_ws, size_t ws_size,
                              hipStream_t stream) {
    const float* h      = (const float*)d_in[0];
    const int*   prev   = (const int*)d_in[1];
    // d_in[2..9]: fw_*/bw_* encoder weights — provably unused (softmax over a
    // broadcast scalar is uniform 1/N regardless of logits).
    const float* Wv     = (const float*)d_in[10];
    const float* fu_W1  = (const float*)d_in[11];
    const float* fu_b1  = (const float*)d_in[12];
    const float* fu_W2  = (const float*)d_in[13];
    const float* fu_b2  = (const float*)d_in[14];
    const float* Wo     = (const float*)d_in[15];
    const float* cratio = (const float*)d_in[16];

    float* out = (float*)d_out;
    float* ws  = (float*)d_ws;
    unsigned short* hbf   = (unsigned short*)(ws + OFF_HBF);
    unsigned short* Xbf   = (unsigned short*)(ws + OFF_XBF);
    unsigned short* Wvbf  = (unsigned short*)(ws + OFF_WBF);   // aliased by Mbf later
    unsigned short* Mbf   = (unsigned short*)(ws + OFF_WBF);
    unsigned short* W1abf = (unsigned short*)(ws + OFF_W1A);
    float* hbar = ws + OFF_HBAR;
    float* cv   = ws + OFF_C;
    float* bias = ws + OFF_BIAS;

    hipMemsetAsync(hbar, 0, 2 * 1024 * sizeof(float), stream);
    k_cast_h<<<128, 256, 0, stream>>>(h, hbf, hbar);
    k_cvec<<<32, 256, 0, stream>>>(Wv, fu_W1, fu_b1, hbar, cv);
    k_cast_w<<<1088, 256, 0, stream>>>(Wv, fu_W1, Wvbf, W1abf);
    k_bias<<<1024, 256, 0, stream>>>(Wo, fu_b2, bias);
    // GEMM1: HF = h @ Wv^T (bf16 MFMA), fused per-head MLP layer1 + GELU -> X
    k_mm<1><<<dim3(32, 16), 256, 0, stream>>>(hbf, Wvbf, Xbf, W1abf, cv, nullptr);
    // M = Wo (x) fu_W2 collapse — after GEMM1 so Mbf can reuse Wvbf space
    k_M<<<dim3(1024, 4), 256, 0, stream>>>(Wo, fu_W2, Mbf);
    // GEMM2: out = X @ M^T + bias
    k_mm<0><<<dim3(32, 16), 256, 0, stream>>>(Xbf, Mbf, out, nullptr, nullptr, bias);
    k_tail<<<8, 256, 0, stream>>>(prev, cratio, out);
}

// Round 3
// 177.283 us; speedup vs baseline: 2.0200x; 1.0932x over previous
//
#include <hip/hip_runtime.h>
#include <hip/hip_bf16.h>

// Problem constants: D=1024, H=16, HD=64, B=2, N=1024, rows = B*N = 2048.

typedef __attribute__((ext_vector_type(8))) short bf16x8;
typedef __attribute__((ext_vector_type(4))) float f32x4;

// ws layout (float offsets). Total ~12.7 MB of the 256 MB workspace.
#define OFF_HBF  0                 // h cast to bf16        [2048][1024] us
#define OFF_XBF  1048576           // X (gelu out) bf16     [2048][1024] us
#define OFF_WVBF 2097152           // Wv bf16               [1024][1024] us
#define OFF_MBF  2621440           // M = Wo(x)fu_W2 bf16   [1024][1024] us
#define OFF_W1A  3145728           // fu_W1[:,:,0:64] bf16  [16][64][64] us
#define OFF_HBAR 3178496           // mean of h over n [2][1024]   (memset w/ bias)
#define OFF_BIAS 3180544           // bias_vec = Wo @ fu_b2 [1024] (memset w/ hbar)
#define OFF_C    3181568           // c vec per (b,head,e) [2][1024]

__device__ __forceinline__ unsigned short f2bf(float f) {
    unsigned int u = __float_as_uint(f);
    u += 0x7fffu + ((u >> 16) & 1u);   // round-to-nearest-even
    return (unsigned short)(u >> 16);
}

__device__ __forceinline__ void async_load16(const void* g, void* l) {
    __builtin_amdgcn_global_load_lds(
        (const __attribute__((address_space(1))) unsigned int*)g,
        (__attribute__((address_space(3))) unsigned int*)l, 16, 0, 0);
}

// ---------------------------------------------------------------------------
// PREP1 (grid 1216): blk<128 : cast h->bf16 + hbar atomic partials (16 rows/blk)
//                    128..1151: cast Wv->bf16 (1024 elems/blk, float4)
//                    1152..1215: cast fu_W1[:,:,0:64] -> W1a bf16
// ---------------------------------------------------------------------------
__global__ __launch_bounds__(256) void k_prep1(const float* __restrict__ h,
                                               const float* __restrict__ Wv,
                                               const float* __restrict__ fu_W1,
                                               unsigned short* __restrict__ hbf,
                                               unsigned short* __restrict__ Wvbf,
                                               unsigned short* __restrict__ W1abf,
                                               float* __restrict__ hbar) {
    int blk = blockIdx.x, tid = threadIdx.x;
    if (blk < 128) {
        int b = blk >> 6, chunk = blk & 63;
        int n0 = chunk * 16, d0 = tid * 4;
        const float* hb = h + (size_t)b * 1048576 + d0;
        unsigned short* ob = hbf + (size_t)b * 1048576 + d0;
        float4 sum = make_float4(0.f, 0.f, 0.f, 0.f);
#pragma unroll
        for (int i = 0; i < 16; ++i) {
            float4 v = *(const float4*)(hb + (size_t)(n0 + i) * 1024);
            sum.x += v.x; sum.y += v.y; sum.z += v.z; sum.w += v.w;
            *(ushort4*)(ob + (size_t)(n0 + i) * 1024) =
                make_ushort4(f2bf(v.x), f2bf(v.y), f2bf(v.z), f2bf(v.w));
        }
        float* hp = hbar + b * 1024 + d0;
        atomicAdd(hp + 0, sum.x * (1.f / 1024.f));
        atomicAdd(hp + 1, sum.y * (1.f / 1024.f));
        atomicAdd(hp + 2, sum.z * (1.f / 1024.f));
        atomicAdd(hp + 3, sum.w * (1.f / 1024.f));
    } else if (blk < 1152) {
        int i0 = (blk - 128) * 1024 + tid * 4;
        float4 v = *(const float4*)(Wv + i0);
        *(ushort4*)(Wvbf + i0) =
            make_ushort4(f2bf(v.x), f2bf(v.y), f2bf(v.z), f2bf(v.w));
    } else {
        int blk2 = blk - 1152;                 // 0..63
        int hh = blk2 >> 2, q = blk2 & 3;
        int e = q * 16 + (tid >> 4);
        int k4 = (tid & 15) * 4;
        float4 v = *(const float4*)(fu_W1 + (size_t)(hh * 64 + e) * 192 + k4);
        *(ushort4*)(W1abf + hh * 4096 + e * 64 + k4) =
            make_ushort4(f2bf(v.x), f2bf(v.y), f2bf(v.z), f2bf(v.w));
    }
}

// ---------------------------------------------------------------------------
// PREP2 (grid 288): blk<256 : M[e',h64+e] = sum_f Wo[e',h64+f]*fu_W2[h,f,e]
//                   (LDS-staged, coalesced; fused bias partial via atomics)
//                   256..287: cvec (per b,head): mf = Wv.hbar, c = b1+(W1b+W1c)mf
// ---------------------------------------------------------------------------
__global__ __launch_bounds__(256) void k_prep2(const float* __restrict__ Wo,
                                               const float* __restrict__ fu_W2,
                                               const float* __restrict__ fu_b2,
                                               const float* __restrict__ Wv,
                                               const float* __restrict__ fu_W1,
                                               const float* __restrict__ fu_b1,
                                               const float* __restrict__ hbar,
                                               unsigned short* __restrict__ Mbf,
                                               float* __restrict__ bias,
                                               float* __restrict__ cvec) {
    __shared__ float smem[8384];   // W2s[64][65] + Wos[64][65] + b2s[64]
    int blk = blockIdx.x, tid = threadIdx.x;
    if (blk < 256) {
        float* W2s = smem;               // [f][e] stride 65
        float* Wos = smem + 4160;        // [r][f] stride 65
        float* b2s = smem + 8320;
        int rc = blk >> 4, hh = blk & 15;
        int r0 = rc * 64;
#pragma unroll
        for (int i = 0; i < 16; ++i) {
            int idx = tid + i * 256;
            int f = idx >> 6, e = idx & 63;
            W2s[f * 65 + e] = fu_W2[hh * 4096 + idx];
            Wos[f * 65 + e] = Wo[(size_t)(r0 + f) * 1024 + hh * 64 + e];
        }
        if (tid < 64) b2s[tid] = fu_b2[hh * 64 + tid];
        __syncthreads();
        // each thread: 2 rows x 8 cols
        int ty = tid >> 3, tx = tid & 7;
        int r1 = 2 * ty, r2 = 2 * ty + 1, e0 = tx * 8;
        float acc0[8], acc1[8];
#pragma unroll
        for (int j = 0; j < 8; ++j) { acc0[j] = 0.f; acc1[j] = 0.f; }
        for (int f = 0; f < 64; ++f) {
            float a0 = Wos[r1 * 65 + f], a1 = Wos[r2 * 65 + f];
            const float* w2r = &W2s[f * 65 + e0];
#pragma unroll
            for (int j = 0; j < 8; ++j) {
                float b = w2r[j];
                acc0[j] += a0 * b;
                acc1[j] += a1 * b;
            }
        }
        unsigned short* m1 = Mbf + (size_t)(r0 + r1) * 1024 + hh * 64 + e0;
        unsigned short* m2 = Mbf + (size_t)(r0 + r2) * 1024 + hh * 64 + e0;
        *(ushort4*)(m1) = make_ushort4(f2bf(acc0[0]), f2bf(acc0[1]), f2bf(acc0[2]), f2bf(acc0[3]));
        *(ushort4*)(m1 + 4) = make_ushort4(f2bf(acc0[4]), f2bf(acc0[5]), f2bf(acc0[6]), f2bf(acc0[7]));
        *(ushort4*)(m2) = make_ushort4(f2bf(acc1[0]), f2bf(acc1[1]), f2bf(acc1[2]), f2bf(acc1[3]));
        *(ushort4*)(m2 + 4) = make_ushort4(f2bf(acc1[4]), f2bf(acc1[5]), f2bf(acc1[6]), f2bf(acc1[7]));
        // fused bias partial: bias[r0+r] += sum_f Wos[r][f]*b2s[f]
        if (tid < 64) {
            float p = 0.f;
#pragma unroll 8
            for (int f = 0; f < 64; ++f) p += Wos[tid * 65 + f] * b2s[f];
            atomicAdd(&bias[r0 + tid], p);
        }
    } else {
        float* psum = smem;              // [64][4]
        float* mf = smem + 256;          // [64]
        int blk2 = blk - 256;
        int b = blk2 >> 4, hh = blk2 & 15;
        int e = tid >> 2, sl = tid & 3;
        const float* wrow = Wv + (size_t)(hh * 64 + e) * 1024;
        const float* hb = hbar + b * 1024;
        float s = 0.f;
        int k0 = sl * 256;
        for (int k = k0; k < k0 + 256; ++k) s += wrow[k] * hb[k];
        psum[e * 4 + sl] = s;
        __syncthreads();
        if (tid < 64)
            mf[tid] = psum[tid * 4] + psum[tid * 4 + 1] + psum[tid * 4 + 2] + psum[tid * 4 + 3];
        __syncthreads();
        if (tid < 64) {
            const float* w1 = fu_W1 + (size_t)(hh * 64 + tid) * 192;
            float acc = fu_b1[hh * 64 + tid];
            for (int k = 0; k < 64; ++k) acc += (w1[64 + k] + w1[128 + k]) * mf[k];
            cvec[b * 1024 + hh * 64 + tid] = acc;
        }
    }
}

// ---------------------------------------------------------------------------
// GEMM: C = A[2048xK=1024] @ W[1024x1024]^T, bf16 MFMA.
// BM=32, BN=64, BK=64, 256 thr (4 waves, each 16x32 = 1x2 16x16 tiles).
// grid (64,16) = 1024 blocks = 4 blocks/CU (2x overlap vs round 2's 2/CU).
// LDS: As[32][64]bf16 (4K) + Bs[64][64]bf16 (8K), XOR-swizzled
//   byte(r,c) = r*128 + (((c>>3)^(r&7))<<4) + (c&7)*2  -> <=2-way conflicts.
// MODE 1: epilogue = per-head 64x64 MLP (HF->LDS A-layout, W1a as B) + c +
//         exact GELU -> X bf16 (coalesced via LDS).
// MODE 0: + bias -> fp32 out via LDS float4 stores; fused tail in block (0,0).
// ---------------------------------------------------------------------------
template <int MODE>
__global__ __launch_bounds__(256) void k_mm(const unsigned short* __restrict__ A,
                                            const unsigned short* __restrict__ Bw,
                                            void* __restrict__ CoutV,
                                            const unsigned short* __restrict__ W1a,
                                            const float* __restrict__ cvec,
                                            const float* __restrict__ bias,
                                            const int* __restrict__ prev_idx,
                                            const float* __restrict__ chain_ratio) {
    __shared__ __align__(16) char smem[12288];
    char* As = smem;            // 4 KB
    char* Bs = smem + 4096;     // 8 KB
    const int tid = threadIdx.x;
    const int w = tid >> 6, lane = tid & 63;
    const int rowBase = blockIdx.x * 32, colBase = blockIdx.y * 64;
    const int wmh = (w >> 1) * 16, wnh = (w & 1) * 32;
    const int lr = lane >> 3;                 // staging row within 8-row chunk
    const int ssrc = ((lane & 7) ^ lr) * 8;   // swizzled source k offset (elems)
    const int m_lane = lane & 15, quad = lane >> 4;

    if (MODE == 0 && blockIdx.x == 0 && blockIdx.y == 0) {
        // fused tail: targets + strength (closed-form: uniform softmax over a
        // broadcast scalar logit -> target 511 / chained prev_idx).
        float* out = (float*)CoutV;
        float cr = chain_ratio[0];
        float thr = floorf(1024.0f / (1.0f + expf(-cr)));
        float strength = 1.0f - logf(1.0f / 1024.0f + 1e-8f);
        for (int i = tid; i < 2048; i += 256) {
            int n = i & 1023;
            float fwd = 511.0f;
            if ((float)n >= thr) {
                int p = prev_idx[i];
                p = p < 0 ? 0 : (p > 1023 ? 1023 : p);
                fwd = (float)p;
            }
            out[2097152 + i] = fwd;
            out[2097152 + 2048 + i] = 511.0f;
            out[2097152 + 4096 + i] = strength;
        }
    }

    const unsigned short* Ag = A + (size_t)(rowBase + w * 8 + lr) * 1024 + ssrc;
    const unsigned short* Bg0 = Bw + (size_t)(colBase + w * 8 + lr) * 1024 + ssrc;
    const unsigned short* Bg1 = Bg0 + (size_t)32 * 1024;
    char* AsW = As + w * 1024;   // wave-uniform LDS staging bases
    char* BsW = Bs + w * 1024;

    f32x4 acc[2];
    acc[0] = (f32x4){0.f, 0.f, 0.f, 0.f};
    acc[1] = (f32x4){0.f, 0.f, 0.f, 0.f};

    for (int k0 = 0; k0 < 1024; k0 += 64) {
        __syncthreads();                       // prev iter's frag reads done
        async_load16(Ag + k0, AsW);
        async_load16(Bg0 + k0, BsW);
        async_load16(Bg1 + k0, BsW + 4096);
        __syncthreads();                       // vmcnt(0) drain before barrier
#pragma unroll
        for (int kh = 0; kh < 2; ++kh) {
            const int seg = kh * 4 + quad;
            const int m = wmh + m_lane;
            bf16x8 af = *(const bf16x8*)(As + m * 128 + ((seg ^ (m & 7)) << 4));
#pragma unroll
            for (int nt = 0; nt < 2; ++nt) {
                int n = wnh + nt * 16 + m_lane;
                bf16x8 bfr = *(const bf16x8*)(Bs + n * 128 + ((seg ^ (n & 7)) << 4));
                acc[nt] = __builtin_amdgcn_mfma_f32_16x16x32_bf16(af, bfr, acc[nt], 0, 0, 0);
            }
        }
    }

    if (MODE == 0) {
        float* out = (float*)CoutV;
        float* Os = (float*)smem;              // [32][68] fp32, 8704 B
        __syncthreads();                       // main-loop LDS reads done
#pragma unroll
        for (int nt = 0; nt < 2; ++nt) {
            int c = wnh + nt * 16 + m_lane;
            float bj = bias[colBase + c];
#pragma unroll
            for (int r4 = 0; r4 < 4; ++r4) {
                int r = wmh + quad * 4 + r4;
                Os[r * 68 + c] = acc[nt][r4] + bj;
            }
        }
        __syncthreads();
#pragma unroll
        for (int j = 0; j < 2; ++j) {
            int sidx = tid + j * 256;
            int r = sidx >> 4, sc = sidx & 15;
            float4 v = *(const float4*)&Os[r * 68 + sc * 4];
            *(float4*)&out[(size_t)(rowBase + r) * 1024 + colBase + sc * 4] = v;
        }
    } else {
        unsigned short* Xbf = (unsigned short*)CoutV;
        const int hh = blockIdx.y;             // head for this 64-col block
        __syncthreads();                       // main-loop LDS reads done
        // stage W1a head block [64 e_out][64 e_in] into Bs (swizzled, async)
        const unsigned short* Wg = W1a + hh * 4096 + (w * 8 + lr) * 64 + ssrc;
        async_load16(Wg, BsW);
        async_load16(Wg + 32 * 64, BsW + 4096);
        // write HF (bf16 of acc) into As in A-fragment (swizzled) layout
#pragma unroll
        for (int nt = 0; nt < 2; ++nt) {
            int c = wnh + nt * 16 + m_lane;
#pragma unroll
            for (int r4 = 0; r4 < 4; ++r4) {
                int r = wmh + quad * 4 + r4;
                *(unsigned short*)(As + r * 128 + (((c >> 3) ^ (r & 7)) << 4) +
                                   (c & 7) * 2) = f2bf(acc[nt][r4]);
            }
        }
        __syncthreads();                       // drains vmcnt -> W1a staged
        f32x4 acc2[2];
        acc2[0] = (f32x4){0.f, 0.f, 0.f, 0.f};
        acc2[1] = (f32x4){0.f, 0.f, 0.f, 0.f};
#pragma unroll
        for (int kh = 0; kh < 2; ++kh) {
            const int seg = kh * 4 + quad;
            const int m = wmh + m_lane;
            bf16x8 af = *(const bf16x8*)(As + m * 128 + ((seg ^ (m & 7)) << 4));
#pragma unroll
            for (int nt = 0; nt < 2; ++nt) {
                int n = wnh + nt * 16 + m_lane;
                bf16x8 bfr = *(const bf16x8*)(Bs + n * 128 + ((seg ^ (n & 7)) << 4));
                acc2[nt] = __builtin_amdgcn_mfma_f32_16x16x32_bf16(af, bfr, acc2[nt], 0, 0, 0);
            }
        }
        __syncthreads();                       // HF reads done; As reusable
        const int b = rowBase >> 10;
#pragma unroll
        for (int nt = 0; nt < 2; ++nt) {
            int c = wnh + nt * 16 + m_lane;
            float cadd = cvec[b * 1024 + hh * 64 + c];
#pragma unroll
            for (int r4 = 0; r4 < 4; ++r4) {
                int r = wmh + quad * 4 + r4;
                float t = acc2[nt][r4] + cadd;
                t = 0.5f * t * (1.0f + erff(t * 0.70710678118654752f));
                *(unsigned short*)(As + r * 128 + c * 2) = f2bf(t);  // plain layout
            }
        }
        __syncthreads();
        // coalesced X store: 32 rows x 8 16B-segs = 256, 1 per thread
        int r = tid >> 3, s = tid & 7;
        float4 v = *(const float4*)(As + r * 128 + s * 16);
        *(float4*)((char*)Xbf + ((size_t)(rowBase + r) * 1024 + colBase + s * 8) * 2) = v;
    }
}

// ---------------------------------------------------------------------------
extern "C" void kernel_launch(void* const* d_in, const int* in_sizes, int n_in,
                              void* d_out, int out_size, void* d_ws, size_t ws_size,
                              hipStream_t stream) {
    const float* h      = (const float*)d_in[0];
    const int*   prev   = (const int*)d_in[1];
    // d_in[2..9]: fw_*/bw_* encoder weights — provably unused (softmax over a
    // broadcast scalar logit is uniform 1/N regardless of the logit value).
    const float* Wv     = (const float*)d_in[10];
    const float* fu_W1  = (const float*)d_in[11];
    const float* fu_b1  = (const float*)d_in[12];
    const float* fu_W2  = (const float*)d_in[13];
    const float* fu_b2  = (const float*)d_in[14];
    const float* Wo     = (const float*)d_in[15];
    const float* cratio = (const float*)d_in[16];

    float* out = (float*)d_out;
    float* ws  = (float*)d_ws;
    unsigned short* hbf   = (unsigned short*)(ws + OFF_HBF);
    unsigned short* Xbf   = (unsigned short*)(ws + OFF_XBF);
    unsigned short* Wvbf  = (unsigned short*)(ws + OFF_WVBF);
    unsigned short* Mbf   = (unsigned short*)(ws + OFF_MBF);
    unsigned short* W1abf = (unsigned short*)(ws + OFF_W1A);
    float* hbar = ws + OFF_HBAR;
    float* bias = ws + OFF_BIAS;
    float* cv   = ws + OFF_C;

    // zero hbar (2048) + bias (1024) — contiguous, one 12 KB memset
    hipMemsetAsync(hbar, 0, 3072 * sizeof(float), stream);
    k_prep1<<<1216, 256, 0, stream>>>(h, Wv, fu_W1, hbf, Wvbf, W1abf, hbar);
    k_prep2<<<288, 256, 0, stream>>>(Wo, fu_W2, fu_b2, Wv, fu_W1, fu_b1, hbar,
                                     Mbf, bias, cv);
    // GEMM1: HF = h @ Wv^T (bf16 MFMA), fused per-head MLP layer1 + GELU -> X
    k_mm<1><<<dim3(64, 16), 256, 0, stream>>>(hbf, Wvbf, Xbf, W1abf, cv,
                                              nullptr, nullptr, nullptr);
    // GEMM2: out = X @ M^T + bias (fu_W2/Wo pre-collapsed into M); fused tail
    k_mm<0><<<dim3(64, 16), 256, 0, stream>>>(Xbf, Mbf, out, nullptr, nullptr,
                                              bias, prev, cratio);
}